// Round 1
// baseline (205.029 us; speedup 1.0000x reference)
//
#include <hip/hip_runtime.h>

#define D_FEAT 128

// Kernel A: build segment offsets from the SORTED macro-id array.
// offsets[m] = first gather index whose macro id >= m; offsets[num_macro] = n_gather.
__global__ void seg_offsets_kernel(const int* __restrict__ mids, int n_gather,
                                   int num_macro, int* __restrict__ offsets) {
    int i = blockIdx.x * blockDim.x + threadIdx.x;
    if (i >= n_gather) return;
    int cur = mids[i];
    int prev = (i == 0) ? -1 : mids[i - 1];
    // Fill boundaries for every segment starting at i (covers empty segments).
    for (int m = prev + 1; m <= cur; ++m) offsets[m] = i;
    if (i == n_gather - 1) {
        for (int m = cur + 1; m <= num_macro; ++m) offsets[m] = n_gather;
    }
}

// Kernel B: one block per macro node. 256 threads = 8 row-groups x 32 lanes.
// Each lane gathers a float4 column slice of its group's rows, accumulates in
// registers, then an 8-way LDS reduction produces the 128-wide mean.
__global__ __launch_bounds__(256)
void pool_mean_kernel(const float* __restrict__ feat,
                      const int* __restrict__ nids,
                      const int* __restrict__ offsets,
                      float* __restrict__ out) {
    const int m     = blockIdx.x;
    const int tid   = threadIdx.x;
    const int g     = tid >> 5;         // row group 0..7
    const int c4    = (tid & 31) << 2;  // column offset (float index), float4 aligned

    const int start = offsets[m];
    const int end   = offsets[m + 1];

    float4 acc = make_float4(0.f, 0.f, 0.f, 0.f);
    for (int r = start + g; r < end; r += 8) {
        const int idx = nids[r];
        const float4 v = *(const float4*)(feat + (size_t)idx * D_FEAT + c4);
        acc.x += v.x; acc.y += v.y; acc.z += v.z; acc.w += v.w;
    }

    __shared__ float red[8][D_FEAT];
    red[g][c4 + 0] = acc.x;
    red[g][c4 + 1] = acc.y;
    red[g][c4 + 2] = acc.z;
    red[g][c4 + 3] = acc.w;
    __syncthreads();

    if (tid < D_FEAT) {
        float s = 0.f;
        #pragma unroll
        for (int k = 0; k < 8; ++k) s += red[k][tid];
        const int cnt = end - start;
        const float inv = (cnt > 0) ? (1.0f / (float)cnt) : 0.0f;
        out[(size_t)m * D_FEAT + tid] = s * inv;   // empty segment -> 0 (matches ref)
    }
}

extern "C" void kernel_launch(void* const* d_in, const int* in_sizes, int n_in,
                              void* d_out, int out_size, void* d_ws, size_t ws_size,
                              hipStream_t stream) {
    const float* feat = (const float*)d_in[0];   // [n_nodes, 128] fp32
    const int*   nids = (const int*)d_in[1];     // [n_gather] int32
    const int*   mids = (const int*)d_in[2];     // [n_gather] int32, sorted
    float*       out  = (float*)d_out;           // [num_macro, 128] fp32

    const int n_gather  = in_sizes[1];
    const int num_macro = out_size / D_FEAT;

    int* offsets = (int*)d_ws;                   // (num_macro + 1) ints

    seg_offsets_kernel<<<(n_gather + 255) / 256, 256, 0, stream>>>(
        mids, n_gather, num_macro, offsets);
    pool_mean_kernel<<<num_macro, 256, 0, stream>>>(feat, nids, offsets, out);
}

// Round 2
// 196.896 us; speedup vs baseline: 1.0413x; 1.0413x over previous
//
#include <hip/hip_runtime.h>

#define D_FEAT 128
#define MAX_CHUNK 1024   // indices staged in LDS per pass (segments are ~32 avg, <100 max)

// Kernel A: build segment offsets from the SORTED macro-id array.
// offsets[m] = first gather index whose macro id >= m; offsets[num_macro] = n_gather.
__global__ void seg_offsets_kernel(const int* __restrict__ mids, int n_gather,
                                   int num_macro, int* __restrict__ offsets) {
    int i = blockIdx.x * blockDim.x + threadIdx.x;
    if (i >= n_gather) return;
    int cur = mids[i];
    int prev = (i == 0) ? -1 : mids[i - 1];
    for (int m = prev + 1; m <= cur; ++m) offsets[m] = i;
    if (i == n_gather - 1) {
        for (int m = cur + 1; m <= num_macro; ++m) offsets[m] = n_gather;
    }
}

// Kernel B: one block per macro node. 256 threads = 8 row-groups x 32 lanes.
// Indices are staged into LDS first (kills the dependent global index load),
// then each lane issues 4 independent float4 gathers per unrolled iteration.
__global__ __launch_bounds__(256)
void pool_mean_kernel(const float* __restrict__ feat,
                      const int* __restrict__ nids,
                      const int* __restrict__ offsets,
                      float* __restrict__ out) {
    const int m    = blockIdx.x;
    const int tid  = threadIdx.x;
    const int g    = tid >> 5;         // row group 0..7
    const int c4   = (tid & 31) << 2;  // float4-aligned column offset

    const int start = offsets[m];
    const int cnt   = offsets[m + 1] - start;

    __shared__ int   s_idx[MAX_CHUNK];
    __shared__ float red[8][D_FEAT];

    float4 acc = make_float4(0.f, 0.f, 0.f, 0.f);

    for (int base = 0; base < cnt; base += MAX_CHUNK) {
        const int chunk = min(cnt - base, MAX_CHUNK);

        // Coalesced staging of this chunk's node ids.
        for (int t = tid; t < chunk; t += 256) s_idx[t] = nids[start + base + t];
        __syncthreads();

        int r = g;
        // 4-wide batched gather: 4 independent loads in flight per lane.
        for (; r + 24 < chunk; r += 32) {
            const int i0 = s_idx[r];
            const int i1 = s_idx[r + 8];
            const int i2 = s_idx[r + 16];
            const int i3 = s_idx[r + 24];
            const float4 v0 = *(const float4*)(feat + (size_t)i0 * D_FEAT + c4);
            const float4 v1 = *(const float4*)(feat + (size_t)i1 * D_FEAT + c4);
            const float4 v2 = *(const float4*)(feat + (size_t)i2 * D_FEAT + c4);
            const float4 v3 = *(const float4*)(feat + (size_t)i3 * D_FEAT + c4);
            acc.x += v0.x + v1.x + v2.x + v3.x;
            acc.y += v0.y + v1.y + v2.y + v3.y;
            acc.z += v0.z + v1.z + v2.z + v3.z;
            acc.w += v0.w + v1.w + v2.w + v3.w;
        }
        // Remainder rows for this group.
        for (; r < chunk; r += 8) {
            const int idx = s_idx[r];
            const float4 v = *(const float4*)(feat + (size_t)idx * D_FEAT + c4);
            acc.x += v.x; acc.y += v.y; acc.z += v.z; acc.w += v.w;
        }
        __syncthreads();   // protect s_idx before next chunk (rare path)
    }

    red[g][c4 + 0] = acc.x;
    red[g][c4 + 1] = acc.y;
    red[g][c4 + 2] = acc.z;
    red[g][c4 + 3] = acc.w;
    __syncthreads();

    if (tid < D_FEAT) {
        float s = 0.f;
        #pragma unroll
        for (int k = 0; k < 8; ++k) s += red[k][tid];
        const float inv = (cnt > 0) ? (1.0f / (float)cnt) : 0.0f;
        out[(size_t)m * D_FEAT + tid] = s * inv;
    }
}

extern "C" void kernel_launch(void* const* d_in, const int* in_sizes, int n_in,
                              void* d_out, int out_size, void* d_ws, size_t ws_size,
                              hipStream_t stream) {
    const float* feat = (const float*)d_in[0];   // [n_nodes, 128] fp32
    const int*   nids = (const int*)d_in[1];     // [n_gather] int32
    const int*   mids = (const int*)d_in[2];     // [n_gather] int32, sorted
    float*       out  = (float*)d_out;           // [num_macro, 128] fp32

    const int n_gather  = in_sizes[1];
    const int num_macro = out_size / D_FEAT;

    int* offsets = (int*)d_ws;                   // (num_macro + 1) ints

    seg_offsets_kernel<<<(n_gather + 255) / 256, 256, 0, stream>>>(
        mids, n_gather, num_macro, offsets);
    pool_mean_kernel<<<num_macro, 256, 0, stream>>>(feat, nids, offsets, out);
}